// Round 1
// baseline (318.222 us; speedup 1.0000x reference)
//
#include <hip/hip_runtime.h>
#include <math.h>

// Problem constants (from reference)
#define MM 129      // mesh points per axis (odd)
#define KP 132      // padded K dim (pad entries zero)
#define NP 512      // points per batch
#define NB 4        // batches

static constexpr double D_PI  = 3.14159265358979323846;
static constexpr double D_L   = 2.0 * D_PI;
static constexpr double D_TAU = 12.0 / ((double)MM * (double)MM);
static constexpr double D_INV4TAU = 1.0 / (4.0 * D_TAU);
// scale/M^2 = 1/(8*pi^2*M^4) folded into W tables
static constexpr double D_F = 1.0 / (8.0 * D_PI * D_PI * (double)MM * (double)MM * (double)MM * (double)MM);

__device__ __forceinline__ void cmac(float2& acc, float2 a, float2 b) {
    acc.x = fmaf(a.x, b.x, fmaf(-a.y, b.y, acc.x));
    acc.y = fmaf(a.x, b.y, fmaf( a.y, b.x, acc.y));
}

// ---------------------------------------------------------------------------
// Kernel 1: per-point periodic-Gaussian sampling + length-129 DFT (both axes).
// A[b,p,k], B[b,p,k] complex, k index = centered frequency (k-64), pad zeroed.
// ---------------------------------------------------------------------------
__global__ __launch_bounds__(128) void k_dft(const float* __restrict__ x,
                                             float2* __restrict__ A,
                                             float2* __restrict__ B) {
    const int bp  = blockIdx.x;       // b*512+p
    const int tid = threadIdx.x;
    const float x0 = x[bp * 2 + 0];
    const float x1 = x[bp * 2 + 1];

    __shared__ float2 g2[MM];   // (ga, gb)
    __shared__ float2 tw[MM];   // (cos, sin) of 2*pi*j/M

    const float inv4tau = (float)D_INV4TAU;
    const float Lf      = (float)D_L;
    for (int a = tid; a < MM; a += 128) {
        float u  = (float)a * (float)(D_L / MM);
        float d0 = x0 - u, d1 = x1 - u;
        float ga = expf(-d0 * d0 * inv4tau)
                 + expf(-(d0 - Lf) * (d0 - Lf) * inv4tau)
                 + expf(-(d0 + Lf) * (d0 + Lf) * inv4tau);
        float gb = expf(-d1 * d1 * inv4tau)
                 + expf(-(d1 - Lf) * (d1 - Lf) * inv4tau)
                 + expf(-(d1 + Lf) * (d1 + Lf) * inv4tau);
        g2[a] = make_float2(ga, gb);
        float th = (float)a * (float)(2.0 * D_PI / MM);
        tw[a] = make_float2(cosf(th), sinf(th));
    }
    __syncthreads();

    const size_t base = (size_t)bp * KP;
    for (int k = tid; k < KP; k += 128) {
        if (k < MM) {
            int kc   = k - 64;
            int step = (kc < 0) ? kc + MM : kc;   // kc mod M, in [0,M)
            int idx  = 0;
            float Ar = 0.f, Ai = 0.f, Br = 0.f, Bi = 0.f;
            for (int a = 0; a < MM; ++a) {
                float2 t = tw[idx];
                float2 g = g2[a];
                Ar = fmaf(g.x,  t.x, Ar);
                Ai = fmaf(-g.x, t.y, Ai);
                Br = fmaf(g.y,  t.x, Br);
                Bi = fmaf(-g.y, t.y, Bi);
                idx += step;
                if (idx >= MM) idx -= MM;
            }
            A[base + k] = make_float2(Ar, Ai);
            B[base + k] = make_float2(Br, Bi);
        } else {
            A[base + k] = make_float2(0.f, 0.f);
            B[base + k] = make_float2(0.f, 0.f);
        }
    }
}

// ---------------------------------------------------------------------------
// Kernel 2: W tables (real), one per channel, with global factor folded in.
// W_c[m,n] = amp_c*4pi/(k2+(mu*shift_c)^2) * deconv(k2)^2 * (scale/M^2)
// ---------------------------------------------------------------------------
__global__ __launch_bounds__(256) void k_w(const float* __restrict__ s0p,
                                           const float* __restrict__ s1p,
                                           const float* __restrict__ a0p,
                                           const float* __restrict__ a1p,
                                           float* __restrict__ W0,
                                           float* __restrict__ W1) {
    int i = blockIdx.x * 256 + threadIdx.x;
    if (i >= KP * KP) return;
    int m = i / KP, n = i % KP;
    float w0 = 0.f, w1 = 0.f;
    if (m < MM && n < MM) {
        float kx = (float)(m - 64), ky = (float)(n - 64);
        float k2  = kx * kx + ky * ky;
        float dec = (float)(D_PI / D_TAU) * expf(k2 * (float)D_TAU);
        float base = dec * dec * (float)(4.0 * D_PI * D_F);
        float s0 = s0p[0], s1 = s1p[0];   // mu0 = mu1 = 1
        w0 = a0p[0] * base / (k2 + s0 * s0);
        w1 = a1p[0] * base / (k2 + s1 * s1);
    }
    W0[i] = w0;
    W1[i] = w1;
}

// ---------------------------------------------------------------------------
// Kernel 3: S_b[m,n] = sum_p A[b,p,m]*B[b,p,n]  (complex outer-product accum).
// Block: (m-tile of 4, batch); 128 threads cover n=0..127, tid<4 also n=128..131.
// ---------------------------------------------------------------------------
__global__ __launch_bounds__(128) void k_s(const float2* __restrict__ A,
                                           const float2* __restrict__ B,
                                           float2* __restrict__ S) {
    const int b   = blockIdx.y;
    const int m0  = blockIdx.x * 4;
    const int tid = threadIdx.x;

    float2 acc[4], acc2[4];
    #pragma unroll
    for (int i = 0; i < 4; ++i) { acc[i] = make_float2(0.f, 0.f); acc2[i] = make_float2(0.f, 0.f); }

    const float2* Ab = A + (size_t)b * NP * KP;
    const float2* Bb = B + (size_t)b * NP * KP;

    for (int p = 0; p < NP; ++p) {
        const float2* ap = Ab + (size_t)p * KP + m0;
        float2 a0 = ap[0], a1 = ap[1], a2 = ap[2], a3 = ap[3];  // uniform
        float2 v = Bb[(size_t)p * KP + tid];
        cmac(acc[0], a0, v); cmac(acc[1], a1, v);
        cmac(acc[2], a2, v); cmac(acc[3], a3, v);
        if (tid < 4) {
            float2 v2 = Bb[(size_t)p * KP + 128 + tid];
            cmac(acc2[0], a0, v2); cmac(acc2[1], a1, v2);
            cmac(acc2[2], a2, v2); cmac(acc2[3], a3, v2);
        }
    }

    float2* Sb = S + (size_t)b * KP * KP;
    #pragma unroll
    for (int i = 0; i < 4; ++i) Sb[(size_t)(m0 + i) * KP + tid] = acc[i];
    if (tid < 4) {
        #pragma unroll
        for (int i = 0; i < 4; ++i) Sb[(size_t)(m0 + i) * KP + 128 + tid] = acc2[i];
    }
}

// ---------------------------------------------------------------------------
// Kernel 4: per point p (8 per block), both channels:
//   e_c = sum_{m,n<129} W_c[m,n] * ( Re(S*conj(A_m B_n)) - |A_m|^2|B_n|^2 )
// ---------------------------------------------------------------------------
__global__ __launch_bounds__(128) void k_final(const float2* __restrict__ A,
                                               const float2* __restrict__ B,
                                               const float2* __restrict__ S,
                                               const float* __restrict__ W0,
                                               const float* __restrict__ W1,
                                               float* __restrict__ out) {
    const int b   = blockIdx.y;
    const int p0  = blockIdx.x * 8;
    const int tid = threadIdx.x;

    __shared__ float2 sA[8][KP];
    __shared__ float2 sB[8][KP];
    for (int idx = tid; idx < 8 * KP; idx += 128) {
        int pi = idx / KP, k = idx % KP;
        size_t g = ((size_t)(b * NP + p0 + pi)) * KP + k;
        sA[pi][k] = A[g];
        sB[pi][k] = B[g];
    }
    __syncthreads();

    float e0[8], e1[8];
    #pragma unroll
    for (int i = 0; i < 8; ++i) { e0[i] = 0.f; e1[i] = 0.f; }

    const float2* Sb = S + (size_t)b * KP * KP;
    for (int m = 0; m < MM; ++m) {
        float2 Am[8];
        #pragma unroll
        for (int pi = 0; pi < 8; ++pi) Am[pi] = sA[pi][m];
        for (int n = tid; n < MM; n += 128) {
            float2 s  = Sb[(size_t)m * KP + n];
            float  w0 = W0[m * KP + n];
            float  w1 = W1[m * KP + n];
            #pragma unroll
            for (int pi = 0; pi < 8; ++pi) {
                float2 a  = Am[pi];
                float2 bb = sB[pi][n];
                float abr = a.x * bb.x - a.y * bb.y;
                float abi = a.x * bb.y + a.y * bb.x;
                float d   = fmaf(s.x, abr, s.y * abi) - fmaf(abr, abr, abi * abi);
                e0[pi] = fmaf(w0, d, e0[pi]);
                e1[pi] = fmaf(w1, d, e1[pi]);
            }
        }
    }

    // reduce 128 threads -> 16 outputs (8 points x 2 channels)
    const int lane = tid & 63, wv = tid >> 6;
    __shared__ float part[2][16];
    #pragma unroll
    for (int pi = 0; pi < 8; ++pi) {
        float r0 = e0[pi], r1 = e1[pi];
        #pragma unroll
        for (int o = 32; o > 0; o >>= 1) {
            r0 += __shfl_down(r0, o, 64);
            r1 += __shfl_down(r1, o, 64);
        }
        if (lane == 0) { part[wv][pi * 2 + 0] = r0; part[wv][pi * 2 + 1] = r1; }
    }
    __syncthreads();
    if (tid < 16) {
        float r = part[0][tid] + part[1][tid];
        int pi = tid >> 1, c = tid & 1;
        out[((size_t)(b * NP + p0 + pi)) * 2 + c] = r;
    }
}

// ---------------------------------------------------------------------------
extern "C" void kernel_launch(void* const* d_in, const int* in_sizes, int n_in,
                              void* d_out, int out_size, void* d_ws, size_t ws_size,
                              hipStream_t stream) {
    const float* x      = (const float*)d_in[0];
    const float* shift0 = (const float*)d_in[1];
    const float* shift1 = (const float*)d_in[2];
    const float* amp0   = (const float*)d_in[3];
    const float* amp1   = (const float*)d_in[4];
    float* out = (float*)d_out;

    // workspace layout (float2-aligned)
    float2* A  = (float2*)d_ws;                 // [NB][NP][KP]
    float2* Bv = A + (size_t)NB * NP * KP;      // [NB][NP][KP]
    float2* S  = Bv + (size_t)NB * NP * KP;     // [NB][KP][KP]
    float*  W0 = (float*)(S + (size_t)NB * KP * KP);  // [KP*KP]
    float*  W1 = W0 + KP * KP;                  // [KP*KP]

    k_dft<<<NB * NP, 128, 0, stream>>>(x, A, Bv);
    k_w<<<(KP * KP + 255) / 256, 256, 0, stream>>>(shift0, shift1, amp0, amp1, W0, W1);
    k_s<<<dim3(KP / 4, NB), 128, 0, stream>>>(A, Bv, S);
    k_final<<<dim3(NP / 8, NB), 128, 0, stream>>>(A, Bv, S, W0, W1, out);
}

// Round 2
// 126.391 us; speedup vs baseline: 2.5178x; 2.5178x over previous
//
#include <hip/hip_runtime.h>
#include <math.h>

// Problem constants (from reference)
#define MM 129      // mesh points per axis (odd)
#define KP 132      // padded K dim (pad entries zero)
#define NP 512      // points per batch
#define NB 4        // batches

static constexpr double D_PI  = 3.14159265358979323846;
static constexpr double D_L   = 2.0 * D_PI;
static constexpr double D_TAU = 12.0 / ((double)MM * (double)MM);
static constexpr double D_INV4TAU = 1.0 / (4.0 * D_TAU);
// scale/M^2 = 1/(8*pi^2*M^4) folded into W tables
static constexpr double D_F = 1.0 / (8.0 * D_PI * D_PI * (double)MM * (double)MM * (double)MM * (double)MM);

__device__ __forceinline__ void cmac(float2& acc, float2 a, float2 b) {
    acc.x = fmaf(a.x, b.x, fmaf(-a.y, b.y, acc.x));
    acc.y = fmaf(a.x, b.y, fmaf( a.y, b.x, acc.y));
}

// ---------------------------------------------------------------------------
// Kernel 0: zero S accumulator + out (both are atomicAdd targets).
// ---------------------------------------------------------------------------
#define S_FLOATS (NB * KP * KP * 2)
#define OUT_FLOATS (NB * NP * 2)
__global__ __launch_bounds__(256) void k_zero(float* __restrict__ S,
                                              float* __restrict__ out) {
    int i = blockIdx.x * 256 + threadIdx.x;
    int stride = gridDim.x * 256;
    for (int j = i; j < S_FLOATS; j += stride) S[j] = 0.f;
    for (int j = i; j < OUT_FLOATS; j += stride) out[j] = 0.f;
}

// ---------------------------------------------------------------------------
// Kernel 1: per-point periodic-Gaussian sampling + length-129 DFT (both axes).
// A[b,p,k], B[b,p,k] complex, k index = centered frequency (k-64), pad zeroed.
// ---------------------------------------------------------------------------
__global__ __launch_bounds__(128) void k_dft(const float* __restrict__ x,
                                             float2* __restrict__ A,
                                             float2* __restrict__ B) {
    const int bp  = blockIdx.x;       // b*512+p
    const int tid = threadIdx.x;
    const float x0 = x[bp * 2 + 0];
    const float x1 = x[bp * 2 + 1];

    __shared__ float2 g2[MM];   // (ga, gb)
    __shared__ float2 tw[MM];   // (cos, sin) of 2*pi*j/M

    const float inv4tau = (float)D_INV4TAU;
    const float Lf      = (float)D_L;
    for (int a = tid; a < MM; a += 128) {
        float u  = (float)a * (float)(D_L / MM);
        float d0 = x0 - u, d1 = x1 - u;
        float ga = expf(-d0 * d0 * inv4tau)
                 + expf(-(d0 - Lf) * (d0 - Lf) * inv4tau)
                 + expf(-(d0 + Lf) * (d0 + Lf) * inv4tau);
        float gb = expf(-d1 * d1 * inv4tau)
                 + expf(-(d1 - Lf) * (d1 - Lf) * inv4tau)
                 + expf(-(d1 + Lf) * (d1 + Lf) * inv4tau);
        g2[a] = make_float2(ga, gb);
        float th = (float)a * (float)(2.0 * D_PI / MM);
        tw[a] = make_float2(cosf(th), sinf(th));
    }
    __syncthreads();

    const size_t base = (size_t)bp * KP;
    for (int k = tid; k < KP; k += 128) {
        if (k < MM) {
            int kc   = k - 64;
            int step = (kc < 0) ? kc + MM : kc;   // kc mod M, in [0,M)
            int idx  = 0;
            float Ar = 0.f, Ai = 0.f, Br = 0.f, Bi = 0.f;
            for (int a = 0; a < MM; ++a) {
                float2 t = tw[idx];
                float2 g = g2[a];
                Ar = fmaf(g.x,  t.x, Ar);
                Ai = fmaf(-g.x, t.y, Ai);
                Br = fmaf(g.y,  t.x, Br);
                Bi = fmaf(-g.y, t.y, Bi);
                idx += step;
                if (idx >= MM) idx -= MM;
            }
            A[base + k] = make_float2(Ar, Ai);
            B[base + k] = make_float2(Br, Bi);
        } else {
            A[base + k] = make_float2(0.f, 0.f);
            B[base + k] = make_float2(0.f, 0.f);
        }
    }
}

// ---------------------------------------------------------------------------
// Kernel 2: W tables (real), one per channel, with global factor folded in.
// ---------------------------------------------------------------------------
__global__ __launch_bounds__(256) void k_w(const float* __restrict__ s0p,
                                           const float* __restrict__ s1p,
                                           const float* __restrict__ a0p,
                                           const float* __restrict__ a1p,
                                           float* __restrict__ W0,
                                           float* __restrict__ W1) {
    int i = blockIdx.x * 256 + threadIdx.x;
    if (i >= KP * KP) return;
    int m = i / KP, n = i % KP;
    float w0 = 0.f, w1 = 0.f;
    if (m < MM && n < MM) {
        float kx = (float)(m - 64), ky = (float)(n - 64);
        float k2  = kx * kx + ky * ky;
        float dec = (float)(D_PI / D_TAU) * expf(k2 * (float)D_TAU);
        float base = dec * dec * (float)(4.0 * D_PI * D_F);
        float s0 = s0p[0], s1 = s1p[0];   // mu0 = mu1 = 1
        w0 = a0p[0] * base / (k2 + s0 * s0);
        w1 = a1p[0] * base / (k2 + s1 * s1);
    }
    W0[i] = w0;
    W1[i] = w1;
}

// ---------------------------------------------------------------------------
// Kernel 3: S_b[m,n] += sum_{p in chunk} A[b,p,m]*B[b,p,n]
// Grid: (m-tile 33, p-chunk 8, batch 4) = 1056 blocks, 128 threads (n = tid).
// n >= 128 entries of B are zero pad -> contribute nothing, skipped.
// ---------------------------------------------------------------------------
#define PCHUNK 64
__global__ __launch_bounds__(128) void k_s(const float2* __restrict__ A,
                                           const float2* __restrict__ B,
                                           float2* __restrict__ S) {
    const int b   = blockIdx.z;
    const int pc  = blockIdx.y;
    const int m0  = blockIdx.x * 4;
    const int tid = threadIdx.x;

    float2 acc[4];
    #pragma unroll
    for (int i = 0; i < 4; ++i) acc[i] = make_float2(0.f, 0.f);

    const float2* Ab = A + (size_t)b * NP * KP;
    const float2* Bb = B + (size_t)b * NP * KP;

    const int pend = pc * PCHUNK + PCHUNK;
    for (int p = pc * PCHUNK; p < pend; ++p) {
        const float2* ap = Ab + (size_t)p * KP + m0;
        float2 a0 = ap[0], a1 = ap[1], a2 = ap[2], a3 = ap[3];  // uniform addr
        float2 v = Bb[(size_t)p * KP + tid];
        cmac(acc[0], a0, v); cmac(acc[1], a1, v);
        cmac(acc[2], a2, v); cmac(acc[3], a3, v);
    }

    float* Sb = (float*)(S + (size_t)b * KP * KP);
    #pragma unroll
    for (int i = 0; i < 4; ++i) {
        atomicAdd(&Sb[((size_t)(m0 + i) * KP + tid) * 2 + 0], acc[i].x);
        atomicAdd(&Sb[((size_t)(m0 + i) * KP + tid) * 2 + 1], acc[i].y);
    }
}

// ---------------------------------------------------------------------------
// Kernel 4: per point p (8 per block), both channels, m-chunked over 4 blocks:
//   e_c += sum_{m in chunk, n<129} W_c[m,n]*( Re(S*conj(A_m B_n)) - |A_m B_n|^2 )
// Grid: (NP/8, 4 m-chunks, NB) = 1024 blocks.
// ---------------------------------------------------------------------------
#define MCHUNK 33
__global__ __launch_bounds__(128) void k_final(const float2* __restrict__ A,
                                               const float2* __restrict__ B,
                                               const float2* __restrict__ S,
                                               const float* __restrict__ W0,
                                               const float* __restrict__ W1,
                                               float* __restrict__ out) {
    const int b   = blockIdx.z;
    const int mc  = blockIdx.y;
    const int p0  = blockIdx.x * 8;
    const int tid = threadIdx.x;

    __shared__ float2 sA[8][KP];
    __shared__ float2 sB[8][KP];
    for (int idx = tid; idx < 8 * KP; idx += 128) {
        int pi = idx / KP, k = idx % KP;
        size_t g = ((size_t)(b * NP + p0 + pi)) * KP + k;
        sA[pi][k] = A[g];
        sB[pi][k] = B[g];
    }
    __syncthreads();

    float e0[8], e1[8];
    #pragma unroll
    for (int i = 0; i < 8; ++i) { e0[i] = 0.f; e1[i] = 0.f; }

    const float2* Sb = S + (size_t)b * KP * KP;
    const int mend = (mc * MCHUNK + MCHUNK < MM) ? mc * MCHUNK + MCHUNK : MM;
    for (int m = mc * MCHUNK; m < mend; ++m) {
        float2 Am[8];
        #pragma unroll
        for (int pi = 0; pi < 8; ++pi) Am[pi] = sA[pi][m];
        for (int n = tid; n < MM; n += 128) {
            float2 s  = Sb[(size_t)m * KP + n];
            float  w0 = W0[m * KP + n];
            float  w1 = W1[m * KP + n];
            #pragma unroll
            for (int pi = 0; pi < 8; ++pi) {
                float2 a  = Am[pi];
                float2 bb = sB[pi][n];
                float abr = a.x * bb.x - a.y * bb.y;
                float abi = a.x * bb.y + a.y * bb.x;
                float d   = fmaf(s.x, abr, s.y * abi) - fmaf(abr, abr, abi * abi);
                e0[pi] = fmaf(w0, d, e0[pi]);
                e1[pi] = fmaf(w1, d, e1[pi]);
            }
        }
    }

    // reduce 128 threads -> 16 partials (8 points x 2 channels), atomic to out
    const int lane = tid & 63, wv = tid >> 6;
    __shared__ float part[2][16];
    #pragma unroll
    for (int pi = 0; pi < 8; ++pi) {
        float r0 = e0[pi], r1 = e1[pi];
        #pragma unroll
        for (int o = 32; o > 0; o >>= 1) {
            r0 += __shfl_down(r0, o, 64);
            r1 += __shfl_down(r1, o, 64);
        }
        if (lane == 0) { part[wv][pi * 2 + 0] = r0; part[wv][pi * 2 + 1] = r1; }
    }
    __syncthreads();
    if (tid < 16) {
        float r = part[0][tid] + part[1][tid];
        int pi = tid >> 1, c = tid & 1;
        atomicAdd(&out[((size_t)(b * NP + p0 + pi)) * 2 + c], r);
    }
}

// ---------------------------------------------------------------------------
extern "C" void kernel_launch(void* const* d_in, const int* in_sizes, int n_in,
                              void* d_out, int out_size, void* d_ws, size_t ws_size,
                              hipStream_t stream) {
    const float* x      = (const float*)d_in[0];
    const float* shift0 = (const float*)d_in[1];
    const float* shift1 = (const float*)d_in[2];
    const float* amp0   = (const float*)d_in[3];
    const float* amp1   = (const float*)d_in[4];
    float* out = (float*)d_out;

    // workspace layout (float2-aligned)
    float2* A  = (float2*)d_ws;                 // [NB][NP][KP]
    float2* Bv = A + (size_t)NB * NP * KP;      // [NB][NP][KP]
    float2* S  = Bv + (size_t)NB * NP * KP;     // [NB][KP][KP]
    float*  W0 = (float*)(S + (size_t)NB * KP * KP);  // [KP*KP]
    float*  W1 = W0 + KP * KP;                  // [KP*KP]

    k_zero<<<256, 256, 0, stream>>>((float*)S, out);
    k_dft<<<NB * NP, 128, 0, stream>>>(x, A, Bv);
    k_w<<<(KP * KP + 255) / 256, 256, 0, stream>>>(shift0, shift1, amp0, amp1, W0, W1);
    k_s<<<dim3(KP / 4, 8, NB), 128, 0, stream>>>(A, Bv, S);
    k_final<<<dim3(NP / 8, 4, NB), 128, 0, stream>>>(A, Bv, S, W0, W1, out);
}